// Round 14
// baseline (28.302 us; speedup 1.0000x reference)
//
#include <hip/hip_runtime.h>

#define NCH   30            // 2*5 + 20
#define NCONF 98
#define IMGF  1470          // floats per image (5880 B)
#define IMG4  368           // staged float4/image (5888 B, aligned overread)
#define NACC  64            // spread accumulator cells
#define ASTR  16            // floats between cells (64 B)
#define LCf 5.0f
#define LNf 0.5f

#define AS1 __attribute__((address_space(1)))
#define AS3 __attribute__((address_space(3)))

// DPP cross-lane on the VALU pipe. bound_ctrl=1: invalid -> 0.
template<int CTRL>
__device__ __forceinline__ float dppf(float v) {
    return __int_as_float(__builtin_amdgcn_update_dpp(
        0, __float_as_int(v), CTRL, 0xF, 0xF, true));
}
#define QP_XOR1 0xB1   // quad_perm(1,0,3,2)
#define QP_XOR2 0x4E   // quad_perm(2,3,0,1)
#define QP_B0   0x00   // quad_perm(0,0,0,0)
#define ROW_ROR4 0x124
#define ROW_ROR8 0x128

__device__ __forceinline__ float rlane(float v, int k) {
    return __int_as_float(__builtin_amdgcn_readlane(__float_as_int(v), k));
}

// Per-image, per-lane partial loss (round-13 proven body).
__device__ __forceinline__ float img_partial(const float* __restrict__ img,
                                             float4 bx, int lab,
                                             volatile unsigned char* sm,
                                             int lane, int t, int q, float cf1)
{
    // ---- no-obj conf^2 partial: slot lane (preloaded) + slot lane+64 ----
    float ns = cf1 * cf1;
    if (lane < NCONF - 64) {
        int s2 = lane + 64;
        int c2 = s2 >> 1, b2 = s2 & 1;
        float cf2 = img[c2 * NCH + b2 * 5 + 4];
        ns += cf2 * cf2;
    }

    const float tx = bx.x, ty = bx.y, tw = bx.z, th = bx.w;
    const float fx = tx * 7.0f, fy = ty * 7.0f;
    const int gxi = (int)fx, gyi = (int)fy;
    const float offx = fx - (float)gxi;
    const float offy = fy - (float)gyi;
    const int cellIdx = gyi * 7 + gxi;
    const float* cell = img + cellIdx * NCH;

    // ---- q0/q1 compute their own box's IOU ----
    float px = 0.f, py = 0.f, pw = 0.f, ph = 0.f, pc = 0.f, iou_own = 0.f;
    if (q < 2) {
        float rx = cell[q * 5 + 0];
        float ry = cell[q * 5 + 1];
        pw       = cell[q * 5 + 2];
        ph       = cell[q * 5 + 3];
        pc       = cell[q * 5 + 4];
        px = (rx + (float)gxi) * (1.0f / 7.0f);
        py = (ry + (float)gyi) * (1.0f / 7.0f);

        float x1a = tx - tw * 0.5f, y1a = ty - th * 0.5f;
        float x2a = tx + tw * 0.5f, y2a = ty + th * 0.5f;
        float x1b = px - pw * 0.5f, y1b = py - ph * 0.5f;
        float x2b = px + pw * 0.5f, y2b = py + ph * 0.5f;
        float iw = fmaxf(fminf(x2a, x2b) - fmaxf(x1a, x1b), 0.0f);
        float ih = fmaxf(fminf(y2a, y2b) - fmaxf(y1a, y1b), 0.0f);
        float inter = iw * ih;
        float uni = tw * th + pw * ph - inter;
        iou_own = inter / fmaxf(uni, 1e-10f);
    }
    const float iou_other = dppf<QP_XOR1>(iou_own);
    int bestq = 0;
    if (q < 2) {
        float i0 = (q == 0) ? iou_own   : iou_other;
        float i1 = (q == 0) ? iou_other : iou_own;
        bestq = (i1 >= i0) ? 1 : 0;      // ties -> last box (ref semantics)
    }
    const int best = __builtin_amdgcn_update_dpp(0, bestq, QP_B0, 0xF, 0xF, true);
    const int s = cellIdx * 2 + best;    // marked slot id

    // ---- box + obj loss on the owning lane ----
    float contrib = 0.0f;
    const float eps = 1e-6f;
    if (q == best) {
        float dx = px - offx, dy = py - offy;
        float dw = sqrtf(fmaxf(pw, eps)) - sqrtf(fmaxf(tw, eps));
        float dh = sqrtf(fmaxf(ph, eps)) - sqrtf(fmaxf(th, eps));
        float box_l = dx * dx + dy * dy + dw * dw + dh * dh;
        float obj_l = (pc - 1.0f) * (pc - 1.0f);
        contrib = LCf * box_l + obj_l;
    }

    // ---- dedup via LDS mask: one winner per distinct slot (wave-local) ----
    if (q == best) sm[s] = (unsigned char)lane;
    asm volatile("s_waitcnt lgkmcnt(0)" ::: "memory");
    __builtin_amdgcn_sched_barrier(0);
    const bool winner = (q == best) && (sm[s] == (unsigned char)lane);
    const unsigned long long bal = __ballot(winner);
    const int mc = __popcll(bal);        // wave-uniform distinct count
    const float ms = winner ? pc * pc : 0.0f;

    // ---- class loss: 5 classes per lane, quad reductions via DPP ----
    {
        float cv[5];
        #pragma unroll
        for (int i = 0; i < 5; ++i) cv[i] = cell[10 + q * 5 + i];
        float m = fmaxf(fmaxf(fmaxf(cv[0], cv[1]), fmaxf(cv[2], cv[3])), cv[4]);
        m = fmaxf(m, dppf<QP_XOR1>(m));
        m = fmaxf(m, dppf<QP_XOR2>(m));
        float esum = 0.f, e2 = 0.f, elab = 0.f;
        #pragma unroll
        for (int i = 0; i < 5; ++i) {
            float e = __expf(cv[i] - m);
            esum += e; e2 += e * e;
            if (q * 5 + i == lab) elab = e;
        }
        esum += dppf<QP_XOR1>(esum);  esum += dppf<QP_XOR2>(esum);
        e2   += dppf<QP_XOR1>(e2);    e2   += dppf<QP_XOR2>(e2);
        elab += dppf<QP_XOR1>(elab);  elab += dppf<QP_XOR2>(elab);
        if (q == 0) {
            float inv = 1.0f / esum;
            contrib += e2 * inv * inv - 2.0f * elab * inv + 1.0f;
        }
    }

    const float invDen = 1.0f / (98.0f - (float)mc);
    return contrib + LNf * (ns - ms) * invDen;
}

// 128 threads = 2 fully independent waves; wave w owns image bid*2+w.
// Aligned over-staging (6 VMEM), wave-local vmcnt waits, no barriers,
// epilogue = one fire-and-forget atomicAdd into a spread accumulator cell.
__global__ __launch_bounds__(128) void yolo_loss_kernel(
    const float* __restrict__ outputs,
    const float* __restrict__ boxes,
    const int*   __restrict__ labels,
    float*       __restrict__ acc)
{
    const int tid  = threadIdx.x;
    const int wave = tid >> 6;
    const int lane = tid & 63;
    const int t    = lane >> 2;      // target 0..15
    const int q    = lane & 3;       // quad role
    const int n    = blockIdx.x * 2 + wave;

    __shared__ __align__(16) float s_img[2 * IMG4 * 4];  // 2 x 5888 B
    __shared__ unsigned char       s_m[2][112];

    // target data loads (position in VMEM queue tolerated by the wait math)
    const float4 bx = reinterpret_cast<const float4*>(boxes)[(size_t)n * 16 + t];
    const int   lab = labels[(size_t)n * 16 + t] - 1;

    // ---- aligned over-staging: 368 float4 from 16B-aligned base (shift 0/8).
    // Overshoot reads next image's first 8 B (in-bounds; last image has shift 8
    // and ends exactly at the buffer end).
    const float* gsrc = outputs + (size_t)n * IMGF;
    const uintptr_t gb = (uintptr_t)gsrc & ~(uintptr_t)15;
    const float4* g4 = reinterpret_cast<const float4*>(gb);
    char* wb = (char*)&s_img[wave * (IMG4 * 4)];
    #pragma unroll
    for (int k = 0; k < 5; ++k) {
        __builtin_amdgcn_global_load_lds(
            (const AS1 void*)(g4 + k * 64 + lane),
            (AS3 void*)(wb + (size_t)k * 1024), 16, 0, 0);
    }
    if (lane < IMG4 - 320) {         // tail: 48 lanes
        __builtin_amdgcn_global_load_lds(
            (const AS1 void*)(g4 + 320 + lane),
            (AS3 void*)(wb + (size_t)5 * 1024), 16, 0, 0);
    }
    const float* img = (const float*)(wb + ((uintptr_t)gsrc - gb));

    // split wait: >=6 of 8 VMEM done; staging insts keep source order (LDS
    // side effects), so rounds 0..3 (4 KB) are landed in any bx/lab placement
    // => cells 0..31 valid (max byte 8+3763 < 4096); slot=lane preload OK.
    asm volatile("s_waitcnt vmcnt(2)" ::: "memory");
    __builtin_amdgcn_sched_barrier(0);
    const float cf1 = img[(lane >> 1) * NCH + (lane & 1) * 5 + 4];

    asm volatile("s_waitcnt vmcnt(0)" ::: "memory");
    __builtin_amdgcn_sched_barrier(0);

    float v = img_partial(img, bx, lab, s_m[wave], lane, t, q, cf1);

    // ---- 64-lane reduce fully on VALU ----
    v += dppf<QP_XOR1>(v);
    v += dppf<QP_XOR2>(v);
    v += dppf<ROW_ROR4>(v);
    v += dppf<ROW_ROR8>(v);
    const float tot = (rlane(v, 0) + rlane(v, 16)) + (rlane(v, 32) + rlane(v, 48));
    // 16384 atomics spread over 64 distinct cache lines across the kernel's
    // lifetime: ~256 adds/line, arrival >> service rate -> no serialization.
    if (lane == 0) atomicAdd(&acc[(n & (NACC - 1)) * ASTR], tot);
}

// Single wave: fixed-order reduce of the 64 cells -> mean.
__global__ __launch_bounds__(64) void finalize_kernel(
    const float* __restrict__ acc, float* __restrict__ out, float invN)
{
    const int lane = threadIdx.x;
    float v = acc[lane * ASTR];
    v += dppf<QP_XOR1>(v);
    v += dppf<QP_XOR2>(v);
    v += dppf<ROW_ROR4>(v);
    v += dppf<ROW_ROR8>(v);
    const float tot = (rlane(v, 0) + rlane(v, 16)) + (rlane(v, 32) + rlane(v, 48));
    if (lane == 0) out[0] = tot * invN;
}

extern "C" void kernel_launch(void* const* d_in, const int* in_sizes, int n_in,
                              void* d_out, int out_size, void* d_ws, size_t ws_size,
                              hipStream_t stream) {
    const float* outputs = (const float*)d_in[0];
    const float* boxes   = (const float*)d_in[1];
    const int*   labels  = (const int*)d_in[2];
    float* out = (float*)d_out;

    const int N = in_sizes[0] / IMGF;   // 16384 images
    float* acc = (float*)d_ws;          // NACC cells, stride ASTR floats

    hipMemsetAsync(acc, 0, NACC * ASTR * sizeof(float), stream); // replay-safe
    yolo_loss_kernel<<<N / 2, 128, 0, stream>>>(outputs, boxes, labels, acc);
    finalize_kernel<<<1, 64, 0, stream>>>(acc, out, 1.0f / (float)N);
}

// Round 15
// 24.573 us; speedup vs baseline: 1.1518x; 1.1518x over previous
//
#include <hip/hip_runtime.h>

#define NCH   30            // 2*5 + 20
#define NCONF 98
#define IMGF  1470          // floats per image (5880 B)
#define LCf 5.0f
#define LNf 0.5f

#define AS1 __attribute__((address_space(1)))
#define AS3 __attribute__((address_space(3)))

// DPP cross-lane on the VALU pipe (not LDS). bound_ctrl=1: invalid -> 0.
template<int CTRL>
__device__ __forceinline__ float dppf(float v) {
    return __int_as_float(__builtin_amdgcn_update_dpp(
        0, __float_as_int(v), CTRL, 0xF, 0xF, true));
}
#define QP_XOR1 0xB1   // quad_perm(1,0,3,2)
#define QP_XOR2 0x4E   // quad_perm(2,3,0,1)
#define QP_B0   0x00   // quad_perm(0,0,0,0): broadcast quad lane0
#define ROW_ROR4 0x124
#define ROW_ROR8 0x128

__device__ __forceinline__ float rlane(float v, int k) {
    return __int_as_float(__builtin_amdgcn_readlane(__float_as_int(v), k));
}

// Per-image, per-lane partial loss. Quad (4 lanes) per target; zero shuffles.
__device__ __forceinline__ float img_partial(const float* __restrict__ img,
                                             float4 bx, int lab,
                                             volatile unsigned char* sm,
                                             int lane, int t, int q, float cf1)
{
    // ---- no-obj conf^2 partial: slot lane (preloaded) + slot lane+64 ----
    float ns = cf1 * cf1;
    if (lane < NCONF - 64) {
        int s2 = lane + 64;
        int c2 = s2 >> 1, b2 = s2 & 1;
        float cf2 = img[c2 * NCH + b2 * 5 + 4];
        ns += cf2 * cf2;
    }

    const float tx = bx.x, ty = bx.y, tw = bx.z, th = bx.w;
    const float fx = tx * 7.0f, fy = ty * 7.0f;
    const int gxi = (int)fx, gyi = (int)fy;
    const float offx = fx - (float)gxi;
    const float offy = fy - (float)gyi;
    const int cellIdx = gyi * 7 + gxi;
    const float* cell = img + cellIdx * NCH;

    // ---- q0/q1 compute their own box's IOU ----
    float px = 0.f, py = 0.f, pw = 0.f, ph = 0.f, pc = 0.f, iou_own = 0.f;
    if (q < 2) {
        float rx = cell[q * 5 + 0];
        float ry = cell[q * 5 + 1];
        pw       = cell[q * 5 + 2];
        ph       = cell[q * 5 + 3];
        pc       = cell[q * 5 + 4];
        px = (rx + (float)gxi) * (1.0f / 7.0f);
        py = (ry + (float)gyi) * (1.0f / 7.0f);

        float x1a = tx - tw * 0.5f, y1a = ty - th * 0.5f;
        float x2a = tx + tw * 0.5f, y2a = ty + th * 0.5f;
        float x1b = px - pw * 0.5f, y1b = py - ph * 0.5f;
        float x2b = px + pw * 0.5f, y2b = py + ph * 0.5f;
        float iw = fmaxf(fminf(x2a, x2b) - fmaxf(x1a, x1b), 0.0f);
        float ih = fmaxf(fminf(y2a, y2b) - fmaxf(y1a, y1b), 0.0f);
        float inter = iw * ih;
        float uni = tw * th + pw * ph - inter;
        iou_own = inter / fmaxf(uni, 1e-10f);
    }
    const float iou_other = dppf<QP_XOR1>(iou_own);   // all lanes active here
    int bestq = 0;
    if (q < 2) {
        float i0 = (q == 0) ? iou_own   : iou_other;
        float i1 = (q == 0) ? iou_other : iou_own;
        bestq = (i1 >= i0) ? 1 : 0;      // ties -> last box (ref semantics)
    }
    const int best = __builtin_amdgcn_update_dpp(0, bestq, QP_B0, 0xF, 0xF, true);
    const int s = cellIdx * 2 + best;                 // marked slot id

    // ---- box + obj loss on the owning lane ----
    float contrib = 0.0f;
    const float eps = 1e-6f;
    if (q == best) {
        float dx = px - offx, dy = py - offy;
        float dw = sqrtf(fmaxf(pw, eps)) - sqrtf(fmaxf(tw, eps));
        float dh = sqrtf(fmaxf(ph, eps)) - sqrtf(fmaxf(th, eps));
        float box_l = dx * dx + dy * dy + dw * dw + dh * dh;
        float obj_l = (pc - 1.0f) * (pc - 1.0f);
        contrib = LCf * box_l + obj_l;
    }

    // ---- dedup via LDS mask: one winner per distinct slot (wave-local) ----
    if (q == best) sm[s] = (unsigned char)lane;
    asm volatile("s_waitcnt lgkmcnt(0)" ::: "memory");
    __builtin_amdgcn_sched_barrier(0);
    const bool winner = (q == best) && (sm[s] == (unsigned char)lane);
    const unsigned long long bal = __ballot(winner);
    const int mc = __popcll(bal);                     // wave-uniform count
    const float ms = winner ? pc * pc : 0.0f;

    // ---- class loss: 5 classes per lane, quad reductions via DPP ----
    {
        float cv[5];
        #pragma unroll
        for (int i = 0; i < 5; ++i) cv[i] = cell[10 + q * 5 + i];
        float m = fmaxf(fmaxf(fmaxf(cv[0], cv[1]), fmaxf(cv[2], cv[3])), cv[4]);
        m = fmaxf(m, dppf<QP_XOR1>(m));
        m = fmaxf(m, dppf<QP_XOR2>(m));
        float esum = 0.f, e2 = 0.f, elab = 0.f;
        #pragma unroll
        for (int i = 0; i < 5; ++i) {
            float e = __expf(cv[i] - m);
            esum += e; e2 += e * e;
            if (q * 5 + i == lab) elab = e;
        }
        esum += dppf<QP_XOR1>(esum);  esum += dppf<QP_XOR2>(esum);
        e2   += dppf<QP_XOR1>(e2);    e2   += dppf<QP_XOR2>(e2);
        elab += dppf<QP_XOR1>(elab);  elab += dppf<QP_XOR2>(elab);
        if (q == 0) {
            float inv = 1.0f / esum;
            contrib += e2 * inv * inv - 2.0f * elab * inv + 1.0f;
        }
    }

    // per-lane fold: division by wave-uniform (98-mc) distributes over the sum
    const float invDen = 1.0f / (98.0f - (float)mc);
    return contrib + LNf * (ns - ms) * invDen;
}

// 128 threads = 2 fully independent waves; wave w owns image bid*2+w.
// Wave-local staging + wave-local vmcnt waits; NO barriers at all.
__global__ __launch_bounds__(128) void yolo_loss_kernel(
    const float* __restrict__ outputs,
    const float* __restrict__ boxes,
    const int*   __restrict__ labels,
    float*       __restrict__ per_img)
{
    const int tid  = threadIdx.x;
    const int wave = tid >> 6;
    const int lane = tid & 63;
    const int t    = lane >> 2;      // target 0..15
    const int q    = lane & 3;       // quad role
    const int n    = blockIdx.x * 2 + wave;   // parity(n) == parity(wave)

    __shared__ __align__(16) float s_img[2 * IMGF];  // 11760 B
    __shared__ unsigned char       s_m[2][112];

    // target data loads (anywhere in the VMEM queue; wait math tolerates it)
    const float4 bx = reinterpret_cast<const float4*>(boxes)[(size_t)n * 16 + t];
    const int   lab = labels[(size_t)n * 16 + t] - 1;

    // ---- wave-local staging: 7 insts, parity-split for 16B alignment ----
    const float* gsrc = outputs + (size_t)n * IMGF;
    char* wbase = (char*)&s_img[wave * IMGF];
    const int odd = wave & 1;
    {
        const float* sgp = odd ? gsrc : (gsrc + IMGF - 2);
        char*        slp = odd ? wbase : (wbase + (size_t)(IMGF - 2) * 4);
        if (lane < 2) {
            __builtin_amdgcn_global_load_lds((const AS1 void*)(sgp + lane),
                                             (AS3 void*)slp, 4, 0, 0);
        }
        const float4* g4 = reinterpret_cast<const float4*>(gsrc + (odd ? 2 : 0));
        char* l4 = wbase + (odd ? 8 : 0);
        #pragma unroll
        for (int k = 0; k < 5; ++k) {
            __builtin_amdgcn_global_load_lds(
                (const AS1 void*)(g4 + k * 64 + lane),
                (AS3 void*)(l4 + (size_t)k * 1024), 16, 0, 0);
        }
        if (lane < 367 - 320) {      // round 5 tail: 47 lanes
            __builtin_amdgcn_global_load_lds(
                (const AS1 void*)(g4 + 320 + lane),
                (AS3 void*)(l4 + (size_t)5 * 1024), 16, 0, 0);
        }
    }

    const float* img = &s_img[wave * IMGF];

    // split wait: in ANY placement of bx/lab, <=2 outstanding => small piece +
    // rounds 0..3 landed => floats 0..959 (cells 0..31) valid; slot=lane OK.
    asm volatile("s_waitcnt vmcnt(2)" ::: "memory");
    __builtin_amdgcn_sched_barrier(0);
    const float cf1 = img[(lane >> 1) * NCH + (lane & 1) * 5 + 4];

    asm volatile("s_waitcnt vmcnt(0)" ::: "memory");
    __builtin_amdgcn_sched_barrier(0);

    float v = img_partial(img, bx, lab, s_m[wave], lane, t, q, cf1);

    // ---- 64-lane reduce fully on VALU: xor1,xor2,ror4,ror8 -> row sums ----
    v += dppf<QP_XOR1>(v);
    v += dppf<QP_XOR2>(v);
    v += dppf<ROW_ROR4>(v);
    v += dppf<ROW_ROR8>(v);
    const float tot = (rlane(v, 0) + rlane(v, 16)) + (rlane(v, 32) + rlane(v, 48));
    if (lane == 0) per_img[n] = tot;
}

__global__ __launch_bounds__(1024) void reduce_mean_kernel(
    const float* __restrict__ per_img, float* __restrict__ out, int N)
{
    __shared__ double sd[16];
    double acc = 0.0;
    const float4* p4 = reinterpret_cast<const float4*>(per_img);
    for (int i = threadIdx.x; i < N / 4; i += 1024) {
        float4 v = p4[i];
        acc += (double)v.x + (double)v.y + (double)v.z + (double)v.w;
    }
    #pragma unroll
    for (int off = 32; off > 0; off >>= 1) acc += __shfl_xor(acc, off);
    if ((threadIdx.x & 63) == 0) sd[threadIdx.x >> 6] = acc;
    __syncthreads();
    if (threadIdx.x == 0) {
        double tsum = 0.0;
        #pragma unroll
        for (int w = 0; w < 16; ++w) tsum += sd[w];
        out[0] = (float)(tsum / (double)N);
    }
}

extern "C" void kernel_launch(void* const* d_in, const int* in_sizes, int n_in,
                              void* d_out, int out_size, void* d_ws, size_t ws_size,
                              hipStream_t stream) {
    const float* outputs = (const float*)d_in[0];
    const float* boxes   = (const float*)d_in[1];
    const int*   labels  = (const int*)d_in[2];
    float* out = (float*)d_out;

    const int N  = in_sizes[0] / IMGF;  // 16384 images
    const int nb = N / 2;               // 8192 blocks, 1 image per wave
    float* per_img = (float*)d_ws;      // N floats

    yolo_loss_kernel<<<nb, 128, 0, stream>>>(outputs, boxes, labels, per_img);
    reduce_mean_kernel<<<1, 1024, 0, stream>>>(per_img, out, N);
}